// Round 12
// baseline (101.430 us; speedup 1.0000x reference)
//
#include <hip/hip_runtime.h>

typedef __bf16  bf16x8  __attribute__((ext_vector_type(8)));
typedef float   f32x4   __attribute__((ext_vector_type(4)));
typedef float   f32x16  __attribute__((ext_vector_type(16)));
typedef short   short8  __attribute__((ext_vector_type(8)));

static __device__ __forceinline__ unsigned short f2bf(float f) {
  union { float f; unsigned int u; } v; v.f = f;
  unsigned int u = v.u;
  u += 0x7fffu + ((u >> 16) & 1u);   // round-to-nearest-even
  return (unsigned short)(u >> 16);
}

// e2m1 decode: code = sign<<3 | e<<1 | m ; values {0,.5,1,1.5,2,3,4,6} * sign
static __device__ __forceinline__ float fp4_decode(int qc) {
  int e = (qc >> 1) & 3;
  float m = (float)(qc & 1);
  float mag = (e == 0) ? (0.5f * m)
                       : ((2.0f + m) * 0.5f * (float)(1 << (e - 1)));
  return (qc & 8) ? -mag : mag;
}

// Fused prep (R4-proven): blocks [0, nblkW/256) dequant W; rest convert x.
__global__ __launch_bounds__(256) void w4a16_prep(
    const int* __restrict__ wq, const float* __restrict__ wsc,
    short* __restrict__ wout, int nblkW,
    const float* __restrict__ x, short* __restrict__ xb, int n8) {
  const int nbW = nblkW >> 8;
  if ((int)blockIdx.x < nbW) {
    int idx = blockIdx.x * 256 + threadIdx.x;
    if (idx >= nblkW) return;
    float s = wsc[idx];
    const int4* qp = (const int4*)wq + (size_t)idx * 4;
    int4 q0 = qp[0], q1 = qp[1], q2 = qp[2], q3 = qp[3];
    short8 r0, r1;
    r0[0] = (short)f2bf(fp4_decode(q0.x) * s);
    r0[1] = (short)f2bf(fp4_decode(q0.y) * s);
    r0[2] = (short)f2bf(fp4_decode(q0.z) * s);
    r0[3] = (short)f2bf(fp4_decode(q0.w) * s);
    r0[4] = (short)f2bf(fp4_decode(q1.x) * s);
    r0[5] = (short)f2bf(fp4_decode(q1.y) * s);
    r0[6] = (short)f2bf(fp4_decode(q1.z) * s);
    r0[7] = (short)f2bf(fp4_decode(q1.w) * s);
    r1[0] = (short)f2bf(fp4_decode(q2.x) * s);
    r1[1] = (short)f2bf(fp4_decode(q2.y) * s);
    r1[2] = (short)f2bf(fp4_decode(q2.z) * s);
    r1[3] = (short)f2bf(fp4_decode(q2.w) * s);
    r1[4] = (short)f2bf(fp4_decode(q3.x) * s);
    r1[5] = (short)f2bf(fp4_decode(q3.y) * s);
    r1[6] = (short)f2bf(fp4_decode(q3.z) * s);
    r1[7] = (short)f2bf(fp4_decode(q3.w) * s);
    short8* op = (short8*)wout + (size_t)idx * 2;
    op[0] = r0;
    op[1] = r1;
  } else {
    int idx = (blockIdx.x - nbW) * 256 + threadIdx.x;
    if (idx >= n8) return;
    const float4* xp = (const float4*)x + (size_t)idx * 2;
    float4 a = xp[0], b = xp[1];
    short8 r;
    r[0] = (short)f2bf(a.x); r[1] = (short)f2bf(a.y);
    r[2] = (short)f2bf(a.z); r[3] = (short)f2bf(a.w);
    r[4] = (short)f2bf(b.x); r[5] = (short)f2bf(b.y);
    r[6] = (short)f2bf(b.z); r[7] = (short)f2bf(b.w);
    ((short8*)xb)[idx] = r;
  }
}

// ---------------------------------------------------------------------------
// C[M,N] = A[M,K] * B[N,K]^T, bf16 in, fp32 out.
// R4's HW-PROVEN skeleton (BM=128 x BN=256, BK=64, 8 waves 2x4, NBUF=3,
// stage-2-ahead, ONE {sched_barrier + vmcnt(6) + s_barrier} per K-tile),
// with the MFMA layer switched 16x16x32 -> 32x32x16:
//  - 2x FLOP per instruction (8.07cy vs 2x4.85cy, m119) => MFMA pipe
//    1242 -> 1033 cyc/tile, and half the MFMA issue slots.
//  - identical LDS bytes & staging; swizzle XOR = lane&7 unchanged.
// Frag layouts (32x32x16 bf16):
//  A/B operand: row/col = lane&31, k = (lane>>5)*8 + j (k-contiguous 16B).
//  C/D (m74/m101 verified): col = lane&31, row=(r&3)+8*(r>>2)+4*(lane>>5).
// Per wave per K-tile: mq2 x nq2 quads x ks4 (K=16 each) = 16 MFMA;
// reads: A 2x4 + B 2x4 = 16 x b128 (chunk c = ks*2 + (lane>>5)).
// ---------------------------------------------------------------------------
#define BM 128
#define BN 256
#define BK 64
#define NBUF 3
#define ASZ (BM * BK)          // 8192 shorts = 16KB
#define BSZ (BN * BK)          // 16384 shorts = 32KB

__global__ __launch_bounds__(512, 1) void w4a16_gemm_32(
    const short* __restrict__ A, const short* __restrict__ B,
    float* __restrict__ C, int M, int N, int K) {
  __shared__ __attribute__((aligned(16))) short As[NBUF * ASZ];  // 48KB
  __shared__ __attribute__((aligned(16))) short Bs[NBUF * BSZ];  // 96KB

  const int tid  = threadIdx.x;
  const int lane = tid & 63;
  const int wid  = tid >> 6;      // 0..7
  const int wr   = wid >> 2;      // 0..1  (M)
  const int wc   = wid & 3;       // 0..3  (N)

  const int bm = blockIdx.y * BM;
  const int bn = blockIdx.x * BN;

  f32x16 acc[2][2] = {};          // [mq][nq] 32x32 quads

  const int l31 = lane & 31;      // frag row/col within 32
  const int kh  = lane >> 5;      // k-half selector
  const int xv  = lane & 7;       // swizzle XOR (row&7 == lane&7 here)

  const size_t rowbytes = (size_t)K * 2;

  // ---- loop-invariant staging addresses (per-thread): only kt varies.
  size_t aoff[2];  int aldso[2];
#pragma unroll
  for (int r = 0; r < 2; ++r) {
    int u = r * 512 + tid;               // 0..1023
    int row = u >> 3, c = u & 7;
    int csrc = c ^ (row & 7);
    aoff[r]  = (size_t)(bm + row) * rowbytes + (size_t)csrc * 16;
    aldso[r] = u * 16;
  }
  size_t boff[4];  int bldso[4];
#pragma unroll
  for (int r = 0; r < 4; ++r) {
    int u = r * 512 + tid;               // 0..2047
    int row = u >> 3, c = u & 7;
    int csrc = c ^ (row & 7);
    boff[r]  = (size_t)(bn + row) * rowbytes + (size_t)csrc * 16;
    bldso[r] = u * 16;
  }

  const char* Ag = (const char*)A;
  const char* Bg = (const char*)B;

#define STAGE_A(bufbase, koff2, r)                                              \
  __builtin_amdgcn_global_load_lds(                                             \
      (const __attribute__((address_space(1))) unsigned int*)(Ag + aoff[r] + (koff2)), \
      (__attribute__((address_space(3))) unsigned int*)((char*)(bufbase) + aldso[r]),  \
      16, 0, 0)
#define STAGE_B(bufbase, koff2, r)                                              \
  __builtin_amdgcn_global_load_lds(                                             \
      (const __attribute__((address_space(1))) unsigned int*)(Bg + boff[r] + (koff2)), \
      (__attribute__((address_space(3))) unsigned int*)((char*)(bufbase) + bldso[r]),  \
      16, 0, 0)

  // swizzled fragment reads: row = base + l31, chunk c = ks*2 + kh
  auto readA = [&](const short* Ab, int mq, int ks) -> bf16x8 {
    int row = wr * 64 + mq * 32 + l31;
    int c = ks * 2 + kh;
    return *(const bf16x8*)((const char*)Ab + (size_t)row * 128 + ((c ^ xv) << 4));
  };
  auto readB = [&](const short* Bb, int nq, int ks) -> bf16x8 {
    int row = wc * 64 + nq * 32 + l31;
    int c = ks * 2 + kh;
    return *(const bf16x8*)((const char*)Bb + (size_t)row * 128 + ((c ^ xv) << 4));
  };

  const int NT = K / BK;   // 64

  // ---- prologue: stage tiles 0 and 1; retire tile 0; publish.
  {
    char* A0 = (char*)As; char* B0 = (char*)Bs;
    char* A1 = (char*)(As + ASZ); char* B1 = (char*)(Bs + BSZ);
    STAGE_A(A0, 0, 0); STAGE_A(A0, 0, 1);
    STAGE_B(B0, 0, 0); STAGE_B(B0, 0, 1); STAGE_B(B0, 0, 2); STAGE_B(B0, 0, 3);
    size_t k2 = (size_t)BK * 2;
    STAGE_A(A1, k2, 0); STAGE_A(A1, k2, 1);
    STAGE_B(B1, k2, 0); STAGE_B(B1, k2, 1); STAGE_B(B1, k2, 2); STAGE_B(B1, k2, 3);
  }
  asm volatile("s_waitcnt vmcnt(6)");      // tile 0 complete, tile 1 in flight
  __builtin_amdgcn_s_barrier();

  int cur = 0, nxt = 2;
  for (int t = 0; t < NT; ++t) {
    const short* Ab = As + cur * ASZ;
    const short* Bb = Bs + cur * BSZ;
    char* An = (char*)(As + nxt * ASZ);
    char* Bn = (char*)(Bs + nxt * BSZ);
    const size_t koff2 = (size_t)(t + 2) * (BK * 2);
    const bool pf = (t + 2) < NT;

    bf16x8 af[2][4], bf[2][4];

    // issue all fragment reads for tile t
#pragma unroll
    for (int mq = 0; mq < 2; ++mq)
#pragma unroll
      for (int ks = 0; ks < 4; ++ks)
        af[mq][ks] = readA(Ab, mq, ks);
#pragma unroll
    for (int nq = 0; nq < 2; ++nq)
#pragma unroll
      for (int ks = 0; ks < 4; ++ks)
        bf[nq][ks] = readB(Bb, nq, ks);

    // issue all 6 stage loads for tile t+2
    if (pf) {
      STAGE_A(An, koff2, 0); STAGE_A(An, koff2, 1);
      STAGE_B(Bn, koff2, 0); STAGE_B(Bn, koff2, 1);
      STAGE_B(Bn, koff2, 2); STAGE_B(Bn, koff2, 3);
    }

    // 16 MFMA (32x32x16); compiler inserts counted lgkmcnt before first uses
    __builtin_amdgcn_s_setprio(1);
#pragma unroll
    for (int mq = 0; mq < 2; ++mq)
#pragma unroll
      for (int nq = 0; nq < 2; ++nq)
#pragma unroll
        for (int ks = 0; ks < 4; ++ks)
          acc[mq][nq] = __builtin_amdgcn_mfma_f32_32x32x16_bf16(
              af[mq][ks], bf[nq][ks], acc[mq][nq], 0, 0, 0);
    __builtin_amdgcn_s_setprio(0);

    // boundary: pin issue order, confirm tile t+1 resident, publish
    if (t < NT - 1) {
      __builtin_amdgcn_sched_barrier(0);
      if (pf) asm volatile("s_waitcnt vmcnt(6)");
      else    asm volatile("s_waitcnt vmcnt(0)");
    }
    __builtin_amdgcn_s_barrier();

    cur = (cur == NBUF - 1) ? 0 : cur + 1;
    nxt = (nxt == NBUF - 1) ? 0 : nxt + 1;
  }

  // ---- epilogue: 32x32 C/D map: col = lane&31,
  //      row = (r&3) + 8*(r>>2) + 4*(lane>>5)
#pragma unroll
  for (int mq = 0; mq < 2; ++mq)
#pragma unroll
    for (int nq = 0; nq < 2; ++nq) {
      int n0 = bn + wc * 64 + nq * 32 + l31;
#pragma unroll
      for (int r = 0; r < 16; ++r) {
        int row = (r & 3) + 8 * (r >> 2) + 4 * kh;
        int m0 = bm + wr * 64 + mq * 32 + row;
        C[(size_t)m0 * N + n0] = acc[mq][nq][r];
      }
    }
}

extern "C" void kernel_launch(void* const* d_in, const int* in_sizes, int n_in,
                              void* d_out, int out_size, void* d_ws, size_t ws_size,
                              hipStream_t stream) {
  const float* x   = (const float*)d_in[0];
  const float* wsc = (const float*)d_in[1];
  const int*   wq  = (const int*)d_in[2];
  float* out = (float*)d_out;

  const int K = 4096;                 // in_features
  const int N = in_sizes[2] / K;      // out_features = 4096
  const int M = in_sizes[0] / K;      // batch*seq = 2048

  // workspace layout: W bf16 [N*K] then X bf16 [M*K]
  short* Wb = (short*)d_ws;
  short* Xb = Wb + (size_t)N * K;

  int nblkW = (N * K) / 16;           // 1048576
  int n8    = (M * K) / 8;            // 1048576
  int gridP = (nblkW >> 8) + ((n8 + 255) >> 8);
  w4a16_prep<<<gridP, 256, 0, stream>>>(wq, wsc, Wb, nblkW, x, Xb, n8);

  dim3 grid(N / BN, M / BM);
  w4a16_gemm_32<<<grid, 512, 0, stream>>>(Xb, Wb, out, M, N, K);
}